// Round 10
// baseline (227.520 us; speedup 1.0000x reference)
//
#include <hip/hip_runtime.h>
#include <hip/hip_bf16.h>
#include <math.h>

#define NROWS 8192
#define DIM   256
#define INV_T 14.285714285714286f   // 1/0.07
#define LOG2E_T 20.60992893360759f  // (1/0.07) * log2(e) -- folded into un
#define EPS_N 1e-8f
#define GRID 512

typedef __attribute__((ext_vector_type(8))) short short8;
typedef __attribute__((ext_vector_type(4))) float f32x4;

typedef const __attribute__((address_space(1))) void g_void;
typedef __attribute__((address_space(3))) void l_void;

__device__ inline unsigned short f2bf(float x) {
    __hip_bfloat16 h = __float2bfloat16(x);
    return __builtin_bit_cast(unsigned short, h);
}

// ---------------------------------------------------------------------------
// ONE kernel, 512 blocks x 256 thr, __launch_bounds__(256,2) + 64KB LDS
// => exactly 2 blocks/CU co-resident => device spin-barrier is safe.
// Phase A: normalize 16 rows/block (un exp2-scaled bf16, vn bf16, diag fp32).
// Barrier:  threadfence + device-scope acq/rel atomic counter spin.
// Phase B: round-7 GEMM core VERBATIM (best measured: 58us, no spill):
//   block = 128 i-rows x 1024 j-cols, 16 j-steps of 64 cols;
//   A 64x256/wave pinned in AGPRs; B double-buffered k-chunked LDS via
//   global_load_lds (0 bank conflicts); 2-barrier j-loop.
// Phase C: done-counter finale computes mean(log(rowsum)-diag).
// Rationale: rounds 2-9 show a constant ~55-60us non-gemm residue regardless
// of kernel count; fusing deletes inter-dispatch overhead and, if the residue
// survives, localizes it inside this single dispatch.
// ---------------------------------------------------------------------------
__global__ __launch_bounds__(256, 2)
void fused_kernel(const float* __restrict__ u, const float* __restrict__ v,
                  unsigned short* __restrict__ un, unsigned short* __restrict__ vn,
                  float* __restrict__ diag, float* __restrict__ rowsum,
                  unsigned int* __restrict__ bar, unsigned int* __restrict__ fin,
                  float* __restrict__ out)
{
    __shared__ unsigned short Bs[2][32][64][8];   // 64 KB
    __shared__ float red[4];
    __shared__ unsigned int lastflag;

    const int t    = threadIdx.x;
    const int lane = t & 63;
    const int wid  = t >> 6;
    const int bid  = blockIdx.x;

    // ================= Phase A: normalize rows 16*bid .. 16*bid+15 =========
    {
        const int r = bid * 16 + (t >> 4);
        const int q = t & 15;
        const float4* u4 = (const float4*)(u + (size_t)r * DIM);
        const float4* v4 = (const float4*)(v + (size_t)r * DIM);
        float4 a0 = u4[q], a1 = u4[q + 16], a2 = u4[q + 32], a3 = u4[q + 48];
        float4 b0 = v4[q], b1 = v4[q + 16], b2 = v4[q + 32], b3 = v4[q + 48];

        auto d4 = [](float4 p, float4 s) {
            return p.x * s.x + p.y * s.y + p.z * s.z + p.w * s.w;
        };
        float ssu = d4(a0, a0) + d4(a1, a1) + d4(a2, a2) + d4(a3, a3);
        float ssv = d4(b0, b0) + d4(b1, b1) + d4(b2, b2) + d4(b3, b3);
        float duv = d4(a0, b0) + d4(a1, b1) + d4(a2, b2) + d4(a3, b3);

        #pragma unroll
        for (int m = 1; m <= 8; m <<= 1) {        // reduce within 16-lane group
            ssu += __shfl_xor(ssu, m);
            ssv += __shfl_xor(ssv, m);
            duv += __shfl_xor(duv, m);
        }

        const float iu  = 1.0f / fmaxf(sqrtf(ssu), EPS_N);
        const float iv  = 1.0f / fmaxf(sqrtf(ssv), EPS_N);
        const float ius = iu * LOG2E_T;

        auto pack = [](float4 x, float s) {
            ushort4 p;
            p.x = f2bf(x.x * s); p.y = f2bf(x.y * s);
            p.z = f2bf(x.z * s); p.w = f2bf(x.w * s);
            return p;
        };
        unsigned short* ur = un + (size_t)r * DIM;
        unsigned short* vr = vn + (size_t)r * DIM;
        *(ushort4*)(ur + q * 4)          = pack(a0, ius);
        *(ushort4*)(ur + (q + 16) * 4)   = pack(a1, ius);
        *(ushort4*)(ur + (q + 32) * 4)   = pack(a2, ius);
        *(ushort4*)(ur + (q + 48) * 4)   = pack(a3, ius);
        *(ushort4*)(vr + q * 4)          = pack(b0, iv);
        *(ushort4*)(vr + (q + 16) * 4)   = pack(b1, iv);
        *(ushort4*)(vr + (q + 32) * 4)   = pack(b2, iv);
        *(ushort4*)(vr + (q + 48) * 4)   = pack(b3, iv);
        if (q == 0) diag[r] = duv * iu * iv * INV_T;
    }

    // ================= device-wide barrier (all 512 blocks co-resident) ====
    __threadfence();
    __syncthreads();
    if (t == 0) {
        __hip_atomic_fetch_add(bar, 1u, __ATOMIC_ACQ_REL,
                               __HIP_MEMORY_SCOPE_AGENT);
        while (__hip_atomic_load(bar, __ATOMIC_ACQUIRE,
                                 __HIP_MEMORY_SCOPE_AGENT) < GRID) {
            __builtin_amdgcn_s_sleep(2);
        }
    }
    __syncthreads();

    // ================= Phase B: round-7 GEMM core ==========================
    const int by = bid & 7;            // XCD id -> j-panel pinned to one L2
    const int bx = bid >> 3;
    const int i0 = bx * 128;
    const int j0 = by * 1024;
    const int wr = wid >> 1;
    const int wc = wid & 1;
    const int lr = lane & 15;          // frag row (A) / frag col (B, C/D)
    const int lg = lane >> 4;          // k-group

    auto stage = [&](int buf, int jt) {
        #pragma unroll
        for (int s = 0; s < 8; ++s) {
            const int kg = wid * 8 + s;
            const unsigned short* src = vn + (size_t)(jt + lane) * DIM + kg * 8;
            __builtin_amdgcn_global_load_lds((g_void*)src,
                (l_void*)&Bs[buf][kg][0][0], 16, 0, 0);
        }
    };

    stage(0, j0);

    short8 av[4][8];
    #pragma unroll
    for (int m = 0; m < 4; ++m) {
        const unsigned short* ar =
            un + (size_t)(i0 + wr * 64 + m * 16 + lr) * DIM + lg * 8;
        #pragma unroll
        for (int k = 0; k < 8; ++k) {
            av[m][k] = *(const short8*)(ar + k * 32);
            asm volatile("" : "+a"(av[m][k]));
        }
    }

    float rs[4][4] = {};

    __syncthreads();   // barrier drain: stage(0) + av loads complete

    int buf = 0;
    for (int js = 0; js < 16; ++js) {
        if (js < 15) stage(buf ^ 1, j0 + (js + 1) * 64);

        f32x4 acc[4][2];
        #pragma unroll
        for (int k = 0; k < 8; ++k) {
            const short8 b0 = *(const short8*)&Bs[buf][k * 4 + lg][wc * 32 + lr][0];
            const short8 b1 = *(const short8*)&Bs[buf][k * 4 + lg][wc * 32 + 16 + lr][0];
            if (k == 0) {
                const f32x4 z = {0.f, 0.f, 0.f, 0.f};
                #pragma unroll
                for (int m = 0; m < 4; ++m) {
                    acc[m][0] = __builtin_amdgcn_mfma_f32_16x16x32_bf16(av[m][0], b0, z, 0, 0, 0);
                    acc[m][1] = __builtin_amdgcn_mfma_f32_16x16x32_bf16(av[m][0], b1, z, 0, 0, 0);
                }
            } else {
                #pragma unroll
                for (int m = 0; m < 4; ++m) {
                    acc[m][0] = __builtin_amdgcn_mfma_f32_16x16x32_bf16(av[m][k], b0, acc[m][0], 0, 0, 0);
                    acc[m][1] = __builtin_amdgcn_mfma_f32_16x16x32_bf16(av[m][k], b1, acc[m][1], 0, 0, 0);
                }
            }
        }

        // acc in log2 domain (scale folded into un) -> raw v_exp_f32
        #pragma unroll
        for (int m = 0; m < 4; ++m)
            #pragma unroll
            for (int n = 0; n < 2; ++n)
                #pragma unroll
                for (int r = 0; r < 4; ++r)
                    rs[m][r] += __builtin_amdgcn_exp2f(acc[m][n][r]);

        __syncthreads();
        buf ^= 1;
    }

    // per-row reduce across the 16 col-lanes; C/D row = lg*4 + r
    #pragma unroll
    for (int m = 0; m < 4; ++m)
        #pragma unroll
        for (int r = 0; r < 4; ++r) {
            float s = rs[m][r];
            s += __shfl_xor(s, 1);
            s += __shfl_xor(s, 2);
            s += __shfl_xor(s, 4);
            s += __shfl_xor(s, 8);
            if (lr == 0)
                atomicAdd(&rowsum[i0 + wr * 64 + m * 16 + lg * 4 + r], s);
        }

    // ================= Phase C: done-counter finale ========================
    __threadfence();
    __syncthreads();
    if (t == 0) {
        unsigned int old = atomicAdd(fin, 1u);
        lastflag = (old == GRID - 1) ? 1u : 0u;
    }
    __syncthreads();
    if (lastflag) {
        __threadfence();
        float c = 0.0f;
        #pragma unroll
        for (int q = 0; q < NROWS / 256; ++q) {
            const int r = t + 256 * q;
            const float sv = __hip_atomic_load(&rowsum[r], __ATOMIC_RELAXED,
                                               __HIP_MEMORY_SCOPE_AGENT);
            c += logf(sv) - diag[r];
        }
        #pragma unroll
        for (int m = 32; m >= 1; m >>= 1) c += __shfl_xor(c, m);
        if (lane == 0) red[wid] = c;
        __syncthreads();
        if (t == 0)
            out[0] = (red[0] + red[1] + red[2] + red[3]) * (1.0f / (float)NROWS);
    }
}

// ---------------------------------------------------------------------------
extern "C" void kernel_launch(void* const* d_in, const int* in_sizes, int n_in,
                              void* d_out, int out_size, void* d_ws, size_t ws_size,
                              hipStream_t stream)
{
    const float* u = (const float*)d_in[0];
    const float* v = (const float*)d_in[1];
    float* out = (float*)d_out;

    char* w = (char*)d_ws;
    unsigned short* un = (unsigned short*)w;                                  // 4 MB
    unsigned short* vn = (unsigned short*)(w + (size_t)NROWS * DIM * 2);      // 4 MB
    float* diag   = (float*)(w + (size_t)NROWS * DIM * 4);                    // 32 KB
    float* rowsum = diag + NROWS;                                             // 32 KB
    unsigned int* bar = (unsigned int*)(rowsum + NROWS);
    unsigned int* fin = bar + 1;

    // zero rowsum + both counters in one async memset (graph-capturable)
    hipMemsetAsync(rowsum, 0, NROWS * sizeof(float) + 2 * sizeof(unsigned int),
                   stream);
    fused_kernel<<<GRID, 256, 0, stream>>>(u, v, un, vn, diag, rowsum,
                                           bar, fin, out);
}